// Round 4
// baseline (196.161 us; speedup 1.0000x reference)
//
#include <hip/hip_runtime.h>
#include <hip/hip_bf16.h>
#include <stdint.h>

// ---------- types ----------
typedef __attribute__((ext_vector_type(8))) short bf16x8;   // 8 bf16 in 4 VGPRs
typedef __attribute__((ext_vector_type(4))) float f32x4;

#define MFMA16(a, b, c) __builtin_amdgcn_mfma_f32_16x16x32_bf16(a, b, c, 0, 0, 0)

// async global->LDS, 16 bytes per lane; LDS dest = wave-uniform base + lane*16
typedef const __attribute__((address_space(1))) unsigned int* as1_u32p;
typedef __attribute__((address_space(3))) unsigned int* as3_u32p;
__device__ __forceinline__ void gl_lds16(const void* g, void* l) {
    __builtin_amdgcn_global_load_lds((as1_u32p)g, (as3_u32p)l, 16, 0, 0);
}

__device__ __forceinline__ unsigned short f2bs(float f) {
    __hip_bfloat16 h = __float2bfloat16(f);   // RNE
    unsigned short s;
    __builtin_memcpy(&s, &h, 2);
    return s;
}

// packed RNE f32x2 -> bf16x2 (v_cvt_pk_bf16_f32 on gfx950)
__device__ __forceinline__ unsigned int pk_bf16(float a, float b) {
    float2 f; f.x = a; f.y = b;
    __hip_bfloat162 h = __float22bfloat162_rn(f);
    unsigned int u;
    __builtin_memcpy(&u, &h, 4);
    return u;
}

// raw v_exp_f32: D = 2^S0 (softmax inputs are well in range)
__device__ __forceinline__ float exp2_raw(float x) {
    float r;
    asm("v_exp_f32 %0, %1" : "=v"(r) : "v"(x));
    return r;
}

// combined softmax scale: DH^-0.5 * log2(e); applied to fp32 scores pre-exp
#define QSCALE 0.18033688f

// ---------- fp32 -> bf16 converts (merged: blocks [0,4096) ZT, [4096,5120) W) ----------
__global__ __launch_bounds__(256) void cvt_k(const float* __restrict__ zt,
                                             const float* __restrict__ w,
                                             unsigned short* __restrict__ ztbf,
                                             unsigned short* __restrict__ wbf,
                                             unsigned short* __restrict__ wtbf) {
    const int bid = blockIdx.x;
    if (bid < 4096) {
        int i = bid * 256 + threadIdx.x;     // one float4 per thread
        const float4 v = ((const float4*)zt)[i];
        ushort4 p;
        p.x = f2bs(v.x); p.y = f2bs(v.y); p.z = f2bs(v.z); p.w = f2bs(v.w);
        ((ushort4*)ztbf)[i] = p;
    } else {
        int i = (bid - 4096) * 256 + threadIdx.x;
        int e = i >> 8;              // W row 0..1023
        int d = (i & 255) << 2;      // col 0..1020
        const float4 v = *(const float4*)(w + e * 1024 + d);
        ushort4 p;
        p.x = f2bs(v.x); p.y = f2bs(v.y); p.z = f2bs(v.z); p.w = f2bs(v.w);
        *(ushort4*)(wbf + e * 1024 + d) = p;
        // wtbf: K-dim (e) permuted within 64-blocks to match ssa's storage perm
        const int ep = (e & ~63) | (4 * (e & 15) + ((e >> 4) & 3));
        wtbf[(size_t)(d + 0) * 1024 + ep] = p.x;
        wtbf[(size_t)(d + 1) * 1024 + ep] = p.y;
        wtbf[(size_t)(d + 2) * 1024 + ep] = p.z;
        wtbf[(size_t)(d + 3) * 1024 + ep] = p.w;
    }
}

// ---------- GEMM: C[M,N] = A[M,K] * B[N,K]^T, tile 128x128, 4 waves, dbuf ----------
// grid (8, 32) = 256 blocks = 1 block/CU; double-buffered staging hides the
// barrier's vmcnt drain behind the 16-MFMA compute of the current k-step.
// EPI 0: C -> ztu (b,h,n,dh_perm) bf16 [packed b64] + ztut (b,h,dh,n_perm) bf16
// EPI 1: C -> out0, out1 fp32
template <int EPI>
__global__ __launch_bounds__(256, 2) void gemm_bt_k(
    const __hip_bfloat16* __restrict__ A, const __hip_bfloat16* __restrict__ B, int K,
    unsigned short* __restrict__ ztu, unsigned short* __restrict__ ztut,
    float* __restrict__ out0, float* __restrict__ out1) {
    __shared__ __attribute__((aligned(16))) __hip_bfloat16 At[2][128 * 32];   // 2x8 KB
    __shared__ __attribute__((aligned(16))) __hip_bfloat16 Bt[2][128 * 32];   // 2x8 KB
    const int bn = blockIdx.x, bm = blockIdx.y;
    const int tid = threadIdx.x;
    const int wave = tid >> 6, lane = tid & 63;
    const int wm = wave >> 1, wn = wave & 1;   // 2x2 waves, each 64x64
    const int quad = lane >> 4, l16 = lane & 15;

    f32x4 acc[4][4] = {};

    // staging: 8 chunks of 1KB per tile; wave w does chunks {2w, 2w+1}
    const int c0 = wave * 2, c1 = c0 + 1;
    const int lr = lane >> 2, lc = (lane & 3) * 8;
    const __hip_bfloat16* Ag0 = A + (size_t)(bm * 128 + c0 * 16 + lr) * K + lc;
    const __hip_bfloat16* Ag1 = A + (size_t)(bm * 128 + c1 * 16 + lr) * K + lc;
    const __hip_bfloat16* Bg0 = B + (size_t)(bn * 128 + c0 * 16 + lr) * K + lc;
    const __hip_bfloat16* Bg1 = B + (size_t)(bn * 128 + c1 * 16 + lr) * K + lc;

    const int nk = K >> 5;
    // prologue: stage k-step 0 into buffer 0
    gl_lds16(Ag0, &At[0][c0 * 512]);
    gl_lds16(Ag1, &At[0][c1 * 512]);
    gl_lds16(Bg0, &Bt[0][c0 * 512]);
    gl_lds16(Bg1, &Bt[0][c1 * 512]);
    __syncthreads();

    for (int kt = 0; kt < nk; ++kt) {
        const int cur = kt & 1;
        if (kt + 1 < nk) {
            const int o = (kt + 1) << 5;
            gl_lds16(Ag0 + o, &At[cur ^ 1][c0 * 512]);
            gl_lds16(Ag1 + o, &At[cur ^ 1][c1 * 512]);
            gl_lds16(Bg0 + o, &Bt[cur ^ 1][c0 * 512]);
            gl_lds16(Bg1 + o, &Bt[cur ^ 1][c1 * 512]);
        }
        bf16x8 af[4], bfr[4];
#pragma unroll
        for (int i = 0; i < 4; ++i)
            af[i] = *(const bf16x8*)&At[cur][(wm * 64 + i * 16 + l16) * 32 + quad * 8];
#pragma unroll
        for (int j = 0; j < 4; ++j)
            bfr[j] = *(const bf16x8*)&Bt[cur][(wn * 64 + j * 16 + l16) * 32 + quad * 8];
#pragma unroll
        for (int i = 0; i < 4; ++i)
#pragma unroll
            for (int j = 0; j < 4; ++j) acc[i][j] = MFMA16(af[i], bfr[j], acc[i][j]);
        __syncthreads();
    }

    if (EPI == 0) {
        const int h = bn * 2 + wn;   // j*16+l16 < 64 -> h is j-independent
#pragma unroll
        for (int i = 0; i < 4; ++i) {
#pragma unroll
            for (int r = 0; r < 4; ++r) {
                const int mm = bm * 128 + wm * 64 + i * 16 + quad * 4 + r;  // token
                const int b = mm >> 11, n = mm & 2047;
                const size_t hb = (size_t)(b * 16 + h) * 131072;
                uint2 pk;
                pk.x = pk_bf16(acc[i][0][r], acc[i][1][r]);
                pk.y = pk_bf16(acc[i][2][r], acc[i][3][r]);
                // ztu: dh stored-permuted (4*l16 + j) -> one packed b64 store
                *(uint2*)(ztu + hb + n * 64 + l16 * 4) = pk;
                // ztut: rows = natural dh, cols = n permuted within 64-blocks
                const int np = (n & ~63) | (4 * (n & 15) + ((n >> 4) & 3));
                unsigned short* zt = ztut + hb + np;
                zt[(size_t)(0 * 16 + l16) * 2048] = (unsigned short)(pk.x & 0xffff);
                zt[(size_t)(1 * 16 + l16) * 2048] = (unsigned short)(pk.x >> 16);
                zt[(size_t)(2 * 16 + l16) * 2048] = (unsigned short)(pk.y & 0xffff);
                zt[(size_t)(3 * 16 + l16) * 2048] = (unsigned short)(pk.y >> 16);
            }
        }
    } else {
#pragma unroll
        for (int i = 0; i < 4; ++i) {
#pragma unroll
            for (int r = 0; r < 4; ++r) {
                const int mm = bm * 128 + wm * 64 + i * 16 + quad * 4 + r;
#pragma unroll
                for (int j = 0; j < 4; ++j) {
                    const int e = bn * 128 + wn * 64 + j * 16 + l16;
                    const float v = acc[i][j][r];
                    out0[(size_t)mm * 1024 + e] = v;
                    out1[(size_t)mm * 1024 + e] = v;
                }
            }
        }
    }
}

// ---------- flash attention ----------
// grid (16 qtiles, 32 bh), 256 threads = 4 waves; each wave owns 32 q-rows
// (2 groups of 16) so K/V fragments are read once and used twice.
// K/V LDS double-buffered + XOR-swizzled (group ^ row&7) -> conflict-free b128.
// Fixed-max softmax: p = v_exp_f32(s * DH^-.5 * log2e); per-lane partial sums,
// one cross-lane reduction in the epilogue.
__global__ __launch_bounds__(256, 2) void attn_k(const unsigned short* __restrict__ ztu,
                                                 const unsigned short* __restrict__ ztut,
                                                 unsigned short* __restrict__ ssa) {
    __shared__ __attribute__((aligned(16))) unsigned short Kt[2][64 * 64];  // [key][d-sw]
    __shared__ __attribute__((aligned(16))) unsigned short Vt[2][64 * 64];  // [d][key-sw]
    __shared__ __attribute__((aligned(16))) unsigned short Pt[4][32 * 72];  // per-wave P
    const int qt = blockIdx.x, bh = blockIdx.y;
    const int tid = threadIdx.x, wave = tid >> 6, lane = tid & 63;
    const int quad = lane >> 4, l16 = lane & 15;
    const unsigned short* base = ztu + (size_t)bh * 131072;
    const unsigned short* baseT = ztut + (size_t)bh * 131072;

    // Q fragments: 2 row-groups x 2 k-chunks (raw, unscaled)
    const int qb = qt * 128 + wave * 32;
    bf16x8 qa[2][2];
#pragma unroll
    for (int g = 0; g < 2; ++g) {
        qa[g][0] = *(const bf16x8*)(base + (qb + g * 16 + l16) * 64 + quad * 8);
        qa[g][1] = *(const bf16x8*)(base + (qb + g * 16 + l16) * 64 + 32 + quad * 8);
    }

    float lsum[2][4] = {};
    f32x4 o[2][4] = {};

    // staging: tile = 8 chunks of 1KB; wave w stages chunks {2w,2w+1} of K and V.
    // chunk c covers rows c*8+(lane>>3); swizzled source group = (lane&7)^(lane>>3)
    const int c0 = wave * 2, c1 = c0 + 1;
    const int lrow = lane >> 3;
    const int sw = (lane & 7) ^ lrow;
    const unsigned short* gK0 = base + (c0 * 8 + lrow) * 64 + sw * 8;
    const unsigned short* gK1 = base + (c1 * 8 + lrow) * 64 + sw * 8;
    const unsigned short* gV0 = baseT + (size_t)(c0 * 8 + lrow) * 2048 + sw * 8;
    const unsigned short* gV1 = baseT + (size_t)(c1 * 8 + lrow) * 2048 + sw * 8;
    unsigned short* pw = &Pt[wave][0];

    // swizzled read offsets (elements)
    const int swq = (quad ^ (l16 & 7));
    const int koff0 = l16 * 64 + swq * 8;          // + {nf,df}*1024 per row-group
    const int koff1 = l16 * 64 + (swq ^ 4) * 8;

    // prologue: stage tile 0 into buffer 0
    gl_lds16(gK0, &Kt[0][c0 * 512]);
    gl_lds16(gK1, &Kt[0][c1 * 512]);
    gl_lds16(gV0, &Vt[0][c0 * 512]);
    gl_lds16(gV1, &Vt[0][c1 * 512]);
    __syncthreads();

    for (int t = 0; t < 32; ++t) {
        const int cur = t & 1;
        if (t + 1 < 32) {
            gl_lds16(gK0 + (t + 1) * 4096, &Kt[cur ^ 1][c0 * 512]);
            gl_lds16(gK1 + (t + 1) * 4096, &Kt[cur ^ 1][c1 * 512]);
            gl_lds16(gV0 + (t + 1) * 64, &Vt[cur ^ 1][c0 * 512]);
            gl_lds16(gV1 + (t + 1) * 64, &Vt[cur ^ 1][c1 * 512]);
        }

        // S = Q * K^T  (32 q x 64 keys), C-layout col(key)=l16, row(q)=quad*4+r
        f32x4 s[2][4];
#pragma unroll
        for (int nf = 0; nf < 4; ++nf) {
            bf16x8 kb0 = *(const bf16x8*)&Kt[cur][nf * 1024 + koff0];
            bf16x8 kb1 = *(const bf16x8*)&Kt[cur][nf * 1024 + koff1];
#pragma unroll
            for (int g = 0; g < 2; ++g) {
                f32x4 z = {0.f, 0.f, 0.f, 0.f};
                z = MFMA16(qa[g][0], kb0, z);
                z = MFMA16(qa[g][1], kb1, z);
                s[g][nf] = z;
            }
        }

        // p = exp2(s*QSCALE); per-lane partial sums; packed b64 LDS write.
        // P stored col = 4*l16 + nf  (matches ztut's key permutation)
#pragma unroll
        for (int g = 0; g < 2; ++g) {
#pragma unroll
            for (int r = 0; r < 4; ++r) {
                const float p0 = exp2_raw(s[g][0][r] * QSCALE);
                const float p1 = exp2_raw(s[g][1][r] * QSCALE);
                const float p2 = exp2_raw(s[g][2][r] * QSCALE);
                const float p3 = exp2_raw(s[g][3][r] * QSCALE);
                lsum[g][r] += (p0 + p1) + (p2 + p3);
                uint2 pk;
                pk.x = pk_bf16(p0, p1);
                pk.y = pk_bf16(p2, p3);
                *(uint2*)&pw[(g * 16 + quad * 4 + r) * 72 + l16 * 4] = pk;
            }
        }
        asm volatile("s_waitcnt lgkmcnt(0)" ::: "memory");

        // O += P * V   (B-frag rows = d, swizzled key chunks)
        bf16x8 pa[2][2];
#pragma unroll
        for (int g = 0; g < 2; ++g) {
            pa[g][0] = *(const bf16x8*)&pw[(g * 16 + l16) * 72 + quad * 8];
            pa[g][1] = *(const bf16x8*)&pw[(g * 16 + l16) * 72 + 32 + quad * 8];
        }
#pragma unroll
        for (int df = 0; df < 4; ++df) {
            bf16x8 vb0 = *(const bf16x8*)&Vt[cur][df * 1024 + koff0];
            bf16x8 vb1 = *(const bf16x8*)&Vt[cur][df * 1024 + koff1];
#pragma unroll
            for (int g = 0; g < 2; ++g) {
                o[g][df] = MFMA16(pa[g][0], vb0, o[g][df]);
                o[g][df] = MFMA16(pa[g][1], vb1, o[g][df]);
            }
        }
        __syncthreads();
    }

    // epilogue: reduce l across the 16 key-lanes, then packed b64 stores.
    // ssa stored col = h*64 + 4*l16 + df  (matches wtbf's e permutation)
    const int b = bh >> 4, h = bh & 15;
#pragma unroll
    for (int g = 0; g < 2; ++g) {
#pragma unroll
        for (int r = 0; r < 4; ++r) {
            float v = lsum[g][r];
            v += __shfl_xor(v, 1);
            v += __shfl_xor(v, 2);
            v += __shfl_xor(v, 4);
            v += __shfl_xor(v, 8);
            const float inv = 1.0f / v;
            const int token = b * 2048 + qt * 128 + wave * 32 + g * 16 + quad * 4 + r;
            uint2 pk;
            pk.x = pk_bf16(o[g][0][r] * inv, o[g][1][r] * inv);
            pk.y = pk_bf16(o[g][2][r] * inv, o[g][3][r] * inv);
            *(uint2*)(ssa + (size_t)token * 1024 + h * 64 + l16 * 4) = pk;
        }
    }
}

// ---------- launch ----------
extern "C" void kernel_launch(void* const* d_in, const int* in_sizes, int n_in,
                              void* d_out, int out_size, void* d_ws, size_t ws_size,
                              hipStream_t stream) {
    const float* ZT = (const float*)d_in[0];  // (2,2048,1024)
    const float* W = (const float*)d_in[1];   // (1024,1024)
    float* out = (float*)d_out;               // 2 x 4194304 fp32
    char* ws = (char*)d_ws;

    unsigned short* ztbf  = (unsigned short*)(ws);                       // 8 MB
    unsigned short* wbf   = (unsigned short*)(ws + 8u * 1024 * 1024);    // 2 MB
    unsigned short* wtbf  = (unsigned short*)(ws + 10u * 1024 * 1024);   // 2 MB
    unsigned short* ztu   = (unsigned short*)(ws + 12u * 1024 * 1024);   // 8 MB (b,h,n,dh_perm)
    unsigned short* ztut  = (unsigned short*)(ws + 20u * 1024 * 1024);   // 8 MB (b,h,dh,n_perm)
    unsigned short* ssabf = (unsigned short*)(ws + 28u * 1024 * 1024);   // 8 MB (e_perm)

    cvt_k<<<5120, 256, 0, stream>>>(ZT, W, ztbf, wbf, wtbf);
    // ZTU = ZT @ W^T
    gemm_bt_k<0><<<dim3(8, 32), 256, 0, stream>>>((const __hip_bfloat16*)ztbf,
                                                  (const __hip_bfloat16*)wbf, 1024, ztu, ztut,
                                                  nullptr, nullptr);
    // flash attention per (bh, qtile of 128 rows), 4 waves, 32 q-rows/wave
    attn_k<<<dim3(16, 32), 256, 0, stream>>>(ztu, ztut, ssabf);
    // mssa = ssa @ W, duplicated output
    gemm_bt_k<1><<<dim3(8, 32), 256, 0, stream>>>((const __hip_bfloat16*)ssabf,
                                                  (const __hip_bfloat16*)wtbf, 1024, nullptr,
                                                  nullptr, out, out + 4194304);
}

// Round 5
// 167.230 us; speedup vs baseline: 1.1730x; 1.1730x over previous
//
#include <hip/hip_runtime.h>
#include <hip/hip_bf16.h>
#include <stdint.h>

// ---------- types ----------
typedef __attribute__((ext_vector_type(8))) short bf16x8;   // 8 bf16 in 4 VGPRs
typedef __attribute__((ext_vector_type(4))) float f32x4;

#define MFMA16(a, b, c) __builtin_amdgcn_mfma_f32_16x16x32_bf16(a, b, c, 0, 0, 0)

// async global->LDS, 16 bytes per lane; LDS dest = wave-uniform base + lane*16
typedef const __attribute__((address_space(1))) unsigned int* as1_u32p;
typedef __attribute__((address_space(3))) unsigned int* as3_u32p;
__device__ __forceinline__ void gl_lds16(const void* g, void* l) {
    __builtin_amdgcn_global_load_lds((as1_u32p)g, (as3_u32p)l, 16, 0, 0);
}

__device__ __forceinline__ unsigned short f2bs(float f) {
    __hip_bfloat16 h = __float2bfloat16(f);   // RNE
    unsigned short s;
    __builtin_memcpy(&s, &h, 2);
    return s;
}

// packed RNE f32x2 -> bf16x2 (v_cvt_pk_bf16_f32 on gfx950)
__device__ __forceinline__ unsigned int pk_bf16(float a, float b) {
    float2 f; f.x = a; f.y = b;
    __hip_bfloat162 h = __float22bfloat162_rn(f);
    unsigned int u;
    __builtin_memcpy(&u, &h, 4);
    return u;
}

// raw v_exp_f32: D = 2^S0 (softmax inputs are well in range)
__device__ __forceinline__ float exp2_raw(float x) {
    float r;
    asm("v_exp_f32 %0, %1" : "=v"(r) : "v"(x));
    return r;
}

// combined softmax scale: DH^-0.5 * log2(e); applied to fp32 scores pre-exp
#define QSCALE 0.18033688f

// ---------- fp32 -> bf16 converts ----------
// blocks [0,4096): ZT straight convert. blocks [4096,4352): W 64x64 tiles,
// wbf straight + wtbf transposed via LDS (coalesced b128 stores, e-permuted).
__global__ __launch_bounds__(256) void cvt_k(const float* __restrict__ zt,
                                             const float* __restrict__ w,
                                             unsigned short* __restrict__ ztbf,
                                             unsigned short* __restrict__ wbf,
                                             unsigned short* __restrict__ wtbf) {
    __shared__ __attribute__((aligned(16))) unsigned short T[64 * 72];  // 9 KB
    const int bid = blockIdx.x;
    const int tid = threadIdx.x;
    if (bid < 4096) {
        int i = bid * 256 + tid;     // one float4 per thread
        const float4 v = ((const float4*)zt)[i];
        ushort4 p;
        p.x = f2bs(v.x); p.y = f2bs(v.y); p.z = f2bs(v.z); p.w = f2bs(v.w);
        ((ushort4*)ztbf)[i] = p;
    } else {
        const int b2 = bid - 4096;               // 256 tiles: 16x16 of 64x64
        const int e0 = (b2 >> 4) * 64, d0 = (b2 & 15) * 64;
        const int el = tid >> 2;                 // 0..63
        const int dl = (tid & 3) * 16;           // 0,16,32,48
        const float* src = w + (size_t)(e0 + el) * 1024 + d0 + dl;
        unsigned short myv[16];
#pragma unroll
        for (int q = 0; q < 4; ++q) {
            const float4 v = *(const float4*)(src + q * 4);
            myv[q * 4 + 0] = f2bs(v.x);
            myv[q * 4 + 1] = f2bs(v.y);
            myv[q * 4 + 2] = f2bs(v.z);
            myv[q * 4 + 3] = f2bs(v.w);
        }
        // wbf straight (two 16B stores)
        *(bf16x8*)(wbf + (size_t)(e0 + el) * 1024 + d0 + dl) = *(const bf16x8*)&myv[0];
        *(bf16x8*)(wbf + (size_t)(e0 + el) * 1024 + d0 + dl + 8) = *(const bf16x8*)&myv[8];
        // LDS transpose: T[d_local][ep_local], ep = 4*(e&15) + (e>>4) within tile
        const int epl = 4 * (el & 15) + (el >> 4);
#pragma unroll
        for (int q = 0; q < 16; ++q) T[(dl + q) * 72 + epl] = myv[q];
        __syncthreads();
        // coalesced wtbf stores: row d, 64 ep contiguous
#pragma unroll
        for (int p = 0; p < 2; ++p) {
            const int idx = p * 256 + tid;
            const int dd = idx >> 3, c = (idx & 7) * 8;
            const bf16x8 v = *(const bf16x8*)&T[dd * 72 + c];
            *(bf16x8*)(wtbf + (size_t)(d0 + dd) * 1024 + e0 + c) = v;
        }
    }
}

// ---------- GEMM: C[M,N] = A[M,K] * B[N,K]^T, tile 64x128, BK=64, 4 waves ----------
// grid (8, 64) = 512 blocks = 2 blocks/CU so barrier drains overlap across blocks.
// EPI 0: C -> ztu (b,h,n,dh_perm) bf16 [packed b64] + ztut via LDS transpose
//        (coalesced b128, natural dh rows, n-permuted cols)
// EPI 1: C -> out0, out1 fp32
template <int EPI>
__global__ __launch_bounds__(256, 2) void gemm_bt_k(
    const __hip_bfloat16* __restrict__ A, const __hip_bfloat16* __restrict__ B, int K,
    unsigned short* __restrict__ ztu, unsigned short* __restrict__ ztut,
    float* __restrict__ out0, float* __restrict__ out1) {
    __shared__ __attribute__((aligned(16))) unsigned short smem[12288];  // 24 KB
    unsigned short* At = smem;          // [2][64][32]  (h-half major)
    unsigned short* Bt = smem + 4096;   // [2][128][32]
    unsigned short* Tb = smem;          // epilogue reuse: [128][72] = 18 KB

    const int bn = blockIdx.x, bm = blockIdx.y;
    const int tid = threadIdx.x;
    const int wave = tid >> 6, lane = tid & 63;
    const int wm = wave >> 1, wn = wave & 1;   // wave tile: 32 rows x 64 cols
    const int quad = lane >> 4, l16 = lane & 15;

    f32x4 acc[2][4] = {};

    // staging (BK=64): A chunks g=wave (16 rows) x h=0,1; B chunks g=2w,2w+1 x h=0,1
    const int lr = lane >> 2, lc = (lane & 3) * 8;
    const __hip_bfloat16* Ag = A + (size_t)(bm * 64 + wave * 16 + lr) * K + lc;
    const __hip_bfloat16* Bg0 = B + (size_t)(bn * 128 + (2 * wave) * 16 + lr) * K + lc;
    const __hip_bfloat16* Bg1 = B + (size_t)(bn * 128 + (2 * wave + 1) * 16 + lr) * K + lc;
    unsigned short* lA = At + wave * 512;
    unsigned short* lB0 = Bt + (2 * wave) * 512;
    unsigned short* lB1 = Bt + (2 * wave + 1) * 512;

    const int nk = K >> 6;
    for (int kt = 0; kt < nk; ++kt) {
        const int ko = kt << 6;
        gl_lds16(Ag + ko, lA);
        gl_lds16(Ag + ko + 32, lA + 2048);
        gl_lds16(Bg0 + ko, lB0);
        gl_lds16(Bg0 + ko + 32, lB0 + 4096);
        gl_lds16(Bg1 + ko, lB1);
        gl_lds16(Bg1 + ko + 32, lB1 + 4096);
        __syncthreads();
        bf16x8 af[2][2], bfr[2][4];
#pragma unroll
        for (int h = 0; h < 2; ++h)
#pragma unroll
            for (int i = 0; i < 2; ++i)
                af[h][i] = *(const bf16x8*)&At[h * 2048 + (wm * 32 + i * 16 + l16) * 32 + quad * 8];
#pragma unroll
        for (int h = 0; h < 2; ++h)
#pragma unroll
            for (int j = 0; j < 4; ++j)
                bfr[h][j] = *(const bf16x8*)&Bt[h * 4096 + (wn * 64 + j * 16 + l16) * 32 + quad * 8];
#pragma unroll
        for (int h = 0; h < 2; ++h)
#pragma unroll
            for (int i = 0; i < 2; ++i)
#pragma unroll
                for (int j = 0; j < 4; ++j) acc[i][j] = MFMA16(af[h][i], bfr[h][j], acc[i][j]);
        __syncthreads();
    }

    if (EPI == 0) {
        const int h = bn * 2 + wn;           // e = bn*128 + wn*64 + j*16+l16 -> j-independent
        const int bb = bm >> 5;              // batch
        const int nb = (bm & 31) * 64;       // token base within batch
        const size_t hb = (size_t)(bb * 16 + h) * 131072;
#pragma unroll
        for (int i = 0; i < 2; ++i) {
#pragma unroll
            for (int r = 0; r < 4; ++r) {
                const int n = nb + wm * 32 + i * 16 + quad * 4 + r;
                uint2 pk;
                pk.x = pk_bf16(acc[i][0][r], acc[i][1][r]);
                pk.y = pk_bf16(acc[i][2][r], acc[i][3][r]);
                // ztu: dh stored-permuted (4*l16 + j) -> one packed b64 store
                *(uint2*)(ztu + hb + n * 64 + l16 * 4) = pk;
                // Tb[e_local][np_local]: natural e rows, permuted token cols
                const int npl = 16 * quad + 4 * r + 2 * wm + i;
                Tb[(wn * 64 + 0 + l16) * 72 + npl] = (unsigned short)(pk.x & 0xffff);
                Tb[(wn * 64 + 16 + l16) * 72 + npl] = (unsigned short)(pk.x >> 16);
                Tb[(wn * 64 + 32 + l16) * 72 + npl] = (unsigned short)(pk.y & 0xffff);
                Tb[(wn * 64 + 48 + l16) * 72 + npl] = (unsigned short)(pk.y >> 16);
            }
        }
        __syncthreads();
        // ztut: coalesced b128 stores, rows = natural dh, cols = permuted tokens
#pragma unroll
        for (int ee = 0; ee < 4; ++ee) {
            const int e_local = wave * 32 + ee * 8 + (lane >> 3);
            const int nc = (lane & 7) * 8;
            const bf16x8 v = *(const bf16x8*)&Tb[e_local * 72 + nc];
            const int hh = bn * 2 + (e_local >> 6);
            const int dh = e_local & 63;
            *(bf16x8*)(ztut + (size_t)(bb * 16 + hh) * 131072 + dh * 2048 + nb + nc) = v;
        }
    } else {
#pragma unroll
        for (int i = 0; i < 2; ++i) {
#pragma unroll
            for (int r = 0; r < 4; ++r) {
                const int mm = bm * 64 + wm * 32 + i * 16 + quad * 4 + r;
#pragma unroll
                for (int j = 0; j < 4; ++j) {
                    const int e = bn * 128 + wn * 64 + j * 16 + l16;
                    const float v = acc[i][j][r];
                    out0[(size_t)mm * 1024 + e] = v;
                    out1[(size_t)mm * 1024 + e] = v;
                }
            }
        }
    }
}

// ---------- flash attention (R3 version — proven) ----------
// grid (16 qtiles, 32 bh), 512 threads = 8 waves; each wave owns 16 q-rows.
// K/V LDS tiles XOR-swizzled (group ^ row&7) -> conflict-free b128 reads.
__global__ __launch_bounds__(512, 4) void attn_k(const unsigned short* __restrict__ ztu,
                                                 const unsigned short* __restrict__ ztut,
                                                 unsigned short* __restrict__ ssa) {
    __shared__ __attribute__((aligned(16))) unsigned short Kt[64 * 64];   // [key][d-swizzled]
    __shared__ __attribute__((aligned(16))) unsigned short Vt[64 * 64];   // [d][key-swizzled]
    __shared__ __attribute__((aligned(16))) unsigned short Pt[8][16 * 72];  // per-wave P
    const int qt = blockIdx.x, bh = blockIdx.y;
    const int tid = threadIdx.x, wave = tid >> 6, lane = tid & 63;
    const int quad = lane >> 4, l16 = lane & 15;
    const unsigned short* base = ztu + (size_t)bh * 131072;
    const unsigned short* baseT = ztut + (size_t)bh * 131072;

    // Q fragments (raw, unscaled): A-layout m=l16, k=quad*8+j
    const int qb = qt * 128 + wave * 16;
    const bf16x8 qa0 = *(const bf16x8*)(base + (qb + l16) * 64 + quad * 8);
    const bf16x8 qa1 = *(const bf16x8*)(base + (qb + l16) * 64 + 32 + quad * 8);

    float lsum[4] = {};
    f32x4 o[4] = {};

    // staging: tile = 8 chunks of 1KB; wave w stages chunk w of K and of V.
    const int lrow = lane >> 3;
    const int sw = (lane & 7) ^ lrow;
    const unsigned short* gK = base + (wave * 8 + lrow) * 64 + sw * 8;
    const unsigned short* gV = baseT + (size_t)(wave * 8 + lrow) * 2048 + sw * 8;
    unsigned short* lK = &Kt[wave * 512];
    unsigned short* lV = &Vt[wave * 512];
    unsigned short* pw = &Pt[wave][0];

    // swizzled read offsets (elements)
    const int swq = (quad ^ (l16 & 7));
    const int koff0 = l16 * 64 + swq * 8;          // + {nf,df}*1024 per fragment row-group
    const int koff1 = l16 * 64 + (swq ^ 4) * 8;

    for (int t = 0; t < 32; ++t) {
        gl_lds16(gK + t * 4096, lK);
        gl_lds16(gV + t * 64, lV);
        __syncthreads();

        // S = Q * K^T  (16 q x 64 keys), C-layout col(key)=l16, row(q)=quad*4+r
        f32x4 s[4];
#pragma unroll
        for (int nf = 0; nf < 4; ++nf) {
            bf16x8 kb0 = *(const bf16x8*)&Kt[nf * 1024 + koff0];
            bf16x8 kb1 = *(const bf16x8*)&Kt[nf * 1024 + koff1];
            f32x4 z = {0.f, 0.f, 0.f, 0.f};
            z = MFMA16(qa0, kb0, z);
            z = MFMA16(qa1, kb1, z);
            s[nf] = z;
        }

        // p = exp2(s*QSCALE); per-lane partial sums; packed b64 LDS write.
        // P stored col = 4*l16 + nf  (matches ztut's key permutation)
#pragma unroll
        for (int r = 0; r < 4; ++r) {
            const float p0 = exp2_raw(s[0][r] * QSCALE);
            const float p1 = exp2_raw(s[1][r] * QSCALE);
            const float p2 = exp2_raw(s[2][r] * QSCALE);
            const float p3 = exp2_raw(s[3][r] * QSCALE);
            lsum[r] += (p0 + p1) + (p2 + p3);
            uint2 pk;
            pk.x = pk_bf16(p0, p1);
            pk.y = pk_bf16(p2, p3);
            *(uint2*)&pw[(quad * 4 + r) * 72 + l16 * 4] = pk;
        }
        asm volatile("s_waitcnt lgkmcnt(0)" ::: "memory");

        // O += P * V   (B-frag rows = d, swizzled key chunks)
        bf16x8 pa0 = *(const bf16x8*)&pw[l16 * 72 + quad * 8];
        bf16x8 pa1 = *(const bf16x8*)&pw[l16 * 72 + 32 + quad * 8];
#pragma unroll
        for (int df = 0; df < 4; ++df) {
            bf16x8 vb0 = *(const bf16x8*)&Vt[df * 1024 + koff0];
            bf16x8 vb1 = *(const bf16x8*)&Vt[df * 1024 + koff1];
            o[df] = MFMA16(pa0, vb0, o[df]);
            o[df] = MFMA16(pa1, vb1, o[df]);
        }
        __syncthreads();
    }

    // epilogue: reduce l across the 16 key-lanes, then packed b64 stores.
    // ssa stored col = h*64 + 4*l16 + df  (matches wtbf's e permutation)
    const int b = bh >> 4, h = bh & 15;
#pragma unroll
    for (int r = 0; r < 4; ++r) {
        float v = lsum[r];
        v += __shfl_xor(v, 1);
        v += __shfl_xor(v, 2);
        v += __shfl_xor(v, 4);
        v += __shfl_xor(v, 8);
        const float inv = 1.0f / v;
        const int token = b * 2048 + qt * 128 + wave * 16 + quad * 4 + r;
        uint2 pk;
        pk.x = pk_bf16(o[0][r] * inv, o[1][r] * inv);
        pk.y = pk_bf16(o[2][r] * inv, o[3][r] * inv);
        *(uint2*)(ssa + (size_t)token * 1024 + h * 64 + l16 * 4) = pk;
    }
}

// ---------- launch ----------
extern "C" void kernel_launch(void* const* d_in, const int* in_sizes, int n_in,
                              void* d_out, int out_size, void* d_ws, size_t ws_size,
                              hipStream_t stream) {
    const float* ZT = (const float*)d_in[0];  // (2,2048,1024)
    const float* W = (const float*)d_in[1];   // (1024,1024)
    float* out = (float*)d_out;               // 2 x 4194304 fp32
    char* ws = (char*)d_ws;

    unsigned short* ztbf  = (unsigned short*)(ws);                       // 8 MB
    unsigned short* wbf   = (unsigned short*)(ws + 8u * 1024 * 1024);    // 2 MB
    unsigned short* wtbf  = (unsigned short*)(ws + 10u * 1024 * 1024);   // 2 MB
    unsigned short* ztu   = (unsigned short*)(ws + 12u * 1024 * 1024);   // 8 MB (b,h,n,dh_perm)
    unsigned short* ztut  = (unsigned short*)(ws + 20u * 1024 * 1024);   // 8 MB (b,h,dh,n_perm)
    unsigned short* ssabf = (unsigned short*)(ws + 28u * 1024 * 1024);   // 8 MB (e_perm)

    cvt_k<<<4352, 256, 0, stream>>>(ZT, W, ztbf, wbf, wtbf);
    // ZTU = ZT @ W^T
    gemm_bt_k<0><<<dim3(8, 64), 256, 0, stream>>>((const __hip_bfloat16*)ztbf,
                                                  (const __hip_bfloat16*)wbf, 1024, ztu, ztut,
                                                  nullptr, nullptr);
    // flash attention per (bh, qtile of 128 rows), 8 waves/block
    attn_k<<<dim3(16, 32), 512, 0, stream>>>(ztu, ztut, ssabf);
    // mssa = ssa @ W, duplicated output
    gemm_bt_k<1><<<dim3(8, 64), 256, 0, stream>>>((const __hip_bfloat16*)ssabf,
                                                  (const __hip_bfloat16*)wtbf, 1024, nullptr,
                                                  nullptr, out, out + 4194304);
}

// Round 6
// 162.761 us; speedup vs baseline: 1.2052x; 1.0275x over previous
//
#include <hip/hip_runtime.h>
#include <hip/hip_bf16.h>
#include <stdint.h>

// ---------- types ----------
typedef __attribute__((ext_vector_type(8))) short bf16x8;   // 8 bf16 in 4 VGPRs
typedef __attribute__((ext_vector_type(4))) float f32x4;

#define MFMA16(a, b, c) __builtin_amdgcn_mfma_f32_16x16x32_bf16(a, b, c, 0, 0, 0)

// async global->LDS, 16 bytes per lane; LDS dest = wave-uniform base + lane*16
typedef const __attribute__((address_space(1))) unsigned int* as1_u32p;
typedef __attribute__((address_space(3))) unsigned int* as3_u32p;
__device__ __forceinline__ void gl_lds16(const void* g, void* l) {
    __builtin_amdgcn_global_load_lds((as1_u32p)g, (as3_u32p)l, 16, 0, 0);
}

__device__ __forceinline__ unsigned short f2bs(float f) {
    __hip_bfloat16 h = __float2bfloat16(f);   // RNE
    unsigned short s;
    __builtin_memcpy(&s, &h, 2);
    return s;
}

// packed RNE f32x2 -> bf16x2 (v_cvt_pk_bf16_f32 on gfx950)
__device__ __forceinline__ unsigned int pk_bf16(float a, float b) {
    float2 f; f.x = a; f.y = b;
    __hip_bfloat162 h = __float22bfloat162_rn(f);
    unsigned int u;
    __builtin_memcpy(&u, &h, 4);
    return u;
}

// raw v_exp_f32: D = 2^S0 (softmax inputs are well in range)
__device__ __forceinline__ float exp2_raw(float x) {
    float r;
    asm("v_exp_f32 %0, %1" : "=v"(r) : "v"(x));
    return r;
}

// combined softmax scale: DH^-0.5 * log2(e); applied to fp32 scores pre-exp
#define QSCALE 0.18033688f

// ---------- W fp32 -> bf16 (straight + transposed/e-permuted) ----------
// 256 blocks of 64x64 tiles; wtbf via LDS transpose, coalesced b128 stores.
__global__ __launch_bounds__(256) void cvt_w_k(const float* __restrict__ w,
                                               unsigned short* __restrict__ wbf,
                                               unsigned short* __restrict__ wtbf) {
    __shared__ __attribute__((aligned(16))) unsigned short T[64 * 72];  // 9 KB
    const int b2 = blockIdx.x;               // 256 tiles: 16x16 of 64x64
    const int tid = threadIdx.x;
    const int e0 = (b2 >> 4) * 64, d0 = (b2 & 15) * 64;
    const int el = tid >> 2;                 // 0..63
    const int dl = (tid & 3) * 16;           // 0,16,32,48
    const float* src = w + (size_t)(e0 + el) * 1024 + d0 + dl;
    unsigned short myv[16];
#pragma unroll
    for (int q = 0; q < 4; ++q) {
        const float4 v = *(const float4*)(src + q * 4);
        myv[q * 4 + 0] = f2bs(v.x);
        myv[q * 4 + 1] = f2bs(v.y);
        myv[q * 4 + 2] = f2bs(v.z);
        myv[q * 4 + 3] = f2bs(v.w);
    }
    // wbf straight (two 16B stores)
    *(bf16x8*)(wbf + (size_t)(e0 + el) * 1024 + d0 + dl) = *(const bf16x8*)&myv[0];
    *(bf16x8*)(wbf + (size_t)(e0 + el) * 1024 + d0 + dl + 8) = *(const bf16x8*)&myv[8];
    // LDS transpose: T[d_local][ep_local], ep = 4*(e&15) + (e>>4) within tile
    const int epl = 4 * (el & 15) + (el >> 4);
#pragma unroll
    for (int q = 0; q < 16; ++q) T[(dl + q) * 72 + epl] = myv[q];
    __syncthreads();
    // coalesced wtbf stores: row d, 64 ep contiguous
#pragma unroll
    for (int p = 0; p < 2; ++p) {
        const int idx = p * 256 + tid;
        const int dd = idx >> 3, c = (idx & 7) * 8;
        const bf16x8 v = *(const bf16x8*)&T[dd * 72 + c];
        *(bf16x8*)(wtbf + (size_t)(d0 + dd) * 1024 + e0 + c) = v;
    }
}

// ---------- GEMM: C[M,N] = A[M,K] * B[N,K]^T, tile 64x128, BK=64, 4 waves ----------
// 1D grid 512, XCD-swizzled: xcd = p&7, bm = xcd*8 + ((p>>3)&7), bn = p>>6.
// EPI 0: A staged from fp32 ZT (fused convert); C -> ztu (b,h,n,dh_perm) bf16
//        + ztut via LDS transpose (coalesced b128, natural dh rows, n-perm cols)
// EPI 1: A staged from bf16 ssa via gl_lds16; C -> out0, out1 fp32
template <int EPI>
__global__ __launch_bounds__(256, 2) void gemm_bt_k(
    const float* __restrict__ Af32, const __hip_bfloat16* __restrict__ Abf,
    const __hip_bfloat16* __restrict__ B,
    unsigned short* __restrict__ ztu, unsigned short* __restrict__ ztut,
    float* __restrict__ out0, float* __restrict__ out1) {
    __shared__ __attribute__((aligned(16))) unsigned short smem[12288];  // 24 KB
    unsigned short* At = smem;          // [2][64][32]  (h-half major)
    unsigned short* Bt = smem + 4096;   // [2][128][32]
    unsigned short* Tb = smem;          // epilogue reuse: [128][72] = 18 KB

    const int p = blockIdx.x;
    const int bm = (p & 7) * 8 + ((p >> 3) & 7);   // same-bm blocks share an XCD
    const int bn = p >> 6;
    const int tid = threadIdx.x;
    const int wave = tid >> 6, lane = tid & 63;
    const int wm = wave >> 1, wn = wave & 1;   // wave tile: 32 rows x 64 cols
    const int quad = lane >> 4, l16 = lane & 15;

    f32x4 acc[2][4] = {};

    // staging: A rows wave*16+lr; B chunks 2w,2w+1; lane covers (lr, lc..lc+7)
    const int lr = lane >> 2, lc = (lane & 3) * 8;
    const float* Agf = Af32 ? Af32 + (size_t)(bm * 64 + wave * 16 + lr) * 1024 + lc : nullptr;
    const __hip_bfloat16* Agb =
        Abf ? Abf + (size_t)(bm * 64 + wave * 16 + lr) * 1024 + lc : nullptr;
    const __hip_bfloat16* Bg0 = B + (size_t)(bn * 128 + (2 * wave) * 16 + lr) * 1024 + lc;
    const __hip_bfloat16* Bg1 = B + (size_t)(bn * 128 + (2 * wave + 1) * 16 + lr) * 1024 + lc;
    unsigned short* lA = At + wave * 512;
    unsigned short* lB0 = Bt + (2 * wave) * 512;
    unsigned short* lB1 = Bt + (2 * wave + 1) * 512;

    for (int kt = 0; kt < 16; ++kt) {
        const int ko = kt << 6;
        if (EPI == 0) {
            // fused fp32->bf16 A staging
#pragma unroll
            for (int h = 0; h < 2; ++h) {
                const float4 v0 = *(const float4*)(Agf + ko + h * 32);
                const float4 v1 = *(const float4*)(Agf + ko + h * 32 + 4);
                uint4 wv;
                wv.x = pk_bf16(v0.x, v0.y);
                wv.y = pk_bf16(v0.z, v0.w);
                wv.z = pk_bf16(v1.x, v1.y);
                wv.w = pk_bf16(v1.z, v1.w);
                *(uint4*)(lA + h * 2048 + lr * 32 + lc) = wv;
            }
        } else {
            gl_lds16(Agb + ko, lA);
            gl_lds16(Agb + ko + 32, lA + 2048);
        }
        gl_lds16(Bg0 + ko, lB0);
        gl_lds16(Bg0 + ko + 32, lB0 + 4096);
        gl_lds16(Bg1 + ko, lB1);
        gl_lds16(Bg1 + ko + 32, lB1 + 4096);
        __syncthreads();
        bf16x8 af[2][2], bfr[2][4];
#pragma unroll
        for (int h = 0; h < 2; ++h)
#pragma unroll
            for (int i = 0; i < 2; ++i)
                af[h][i] = *(const bf16x8*)&At[h * 2048 + (wm * 32 + i * 16 + l16) * 32 + quad * 8];
#pragma unroll
        for (int h = 0; h < 2; ++h)
#pragma unroll
            for (int j = 0; j < 4; ++j)
                bfr[h][j] = *(const bf16x8*)&Bt[h * 4096 + (wn * 64 + j * 16 + l16) * 32 + quad * 8];
#pragma unroll
        for (int h = 0; h < 2; ++h)
#pragma unroll
            for (int i = 0; i < 2; ++i)
#pragma unroll
                for (int j = 0; j < 4; ++j) acc[i][j] = MFMA16(af[h][i], bfr[h][j], acc[i][j]);
        __syncthreads();
    }

    if (EPI == 0) {
        const int h = bn * 2 + wn;           // e = bn*128 + wn*64 + j*16+l16 -> j-independent
        const int bb = bm >> 5;              // batch
        const int nb = (bm & 31) * 64;       // token base within batch
        const size_t hb = (size_t)(bb * 16 + h) * 131072;
#pragma unroll
        for (int i = 0; i < 2; ++i) {
#pragma unroll
            for (int r = 0; r < 4; ++r) {
                const int n = nb + wm * 32 + i * 16 + quad * 4 + r;
                uint2 pk;
                pk.x = pk_bf16(acc[i][0][r], acc[i][1][r]);
                pk.y = pk_bf16(acc[i][2][r], acc[i][3][r]);
                // ztu: dh stored-permuted (4*l16 + j) -> one packed b64 store
                *(uint2*)(ztu + hb + n * 64 + l16 * 4) = pk;
                // Tb[e_local][np_local]: natural e rows, permuted token cols
                const int npl = 16 * quad + 4 * r + 2 * wm + i;
                Tb[(wn * 64 + 0 + l16) * 72 + npl] = (unsigned short)(pk.x & 0xffff);
                Tb[(wn * 64 + 16 + l16) * 72 + npl] = (unsigned short)(pk.x >> 16);
                Tb[(wn * 64 + 32 + l16) * 72 + npl] = (unsigned short)(pk.y & 0xffff);
                Tb[(wn * 64 + 48 + l16) * 72 + npl] = (unsigned short)(pk.y >> 16);
            }
        }
        __syncthreads();
        // ztut: coalesced b128 stores, rows = natural dh, cols = permuted tokens
#pragma unroll
        for (int ee = 0; ee < 4; ++ee) {
            const int e_local = wave * 32 + ee * 8 + (lane >> 3);
            const int nc = (lane & 7) * 8;
            const bf16x8 v = *(const bf16x8*)&Tb[e_local * 72 + nc];
            const int hh = bn * 2 + (e_local >> 6);
            const int dh = e_local & 63;
            *(bf16x8*)(ztut + (size_t)(bb * 16 + hh) * 131072 + dh * 2048 + nb + nc) = v;
        }
    } else {
#pragma unroll
        for (int i = 0; i < 2; ++i) {
#pragma unroll
            for (int r = 0; r < 4; ++r) {
                const int mm = bm * 64 + wm * 32 + i * 16 + quad * 4 + r;
#pragma unroll
                for (int j = 0; j < 4; ++j) {
                    const int e = bn * 128 + wn * 64 + j * 16 + l16;
                    const float v = acc[i][j][r];
                    out0[(size_t)mm * 1024 + e] = v;
                    out1[(size_t)mm * 1024 + e] = v;
                }
            }
        }
    }
}

// ---------- flash attention ----------
// 1D grid 512, XCD-swizzled: xcd = p&7 owns bh in [4*xcd, 4*xcd+4) -> K/V
// (2 MB/XCD) stays L2-resident. 256 threads = 4 waves; each wave owns 32 q-rows
// (2 groups of 16) so K/V fragments are read once, used twice. Single-buffered.
// K/V LDS XOR-swizzled (group ^ row&7) -> conflict-free b128 reads.
__global__ __launch_bounds__(256, 4) void attn_k(const unsigned short* __restrict__ ztu,
                                                 const unsigned short* __restrict__ ztut,
                                                 unsigned short* __restrict__ ssa) {
    __shared__ __attribute__((aligned(16))) unsigned short Kt[64 * 64];   // [key][d-sw]
    __shared__ __attribute__((aligned(16))) unsigned short Vt[64 * 64];   // [d][key-sw]
    __shared__ __attribute__((aligned(16))) unsigned short Pt[4][32 * 72];  // per-wave P
    const int p = blockIdx.x;
    const int ii = p >> 3;
    const int bh = (p & 7) * 4 + (ii >> 4);
    const int qt = ii & 15;
    const int tid = threadIdx.x, wave = tid >> 6, lane = tid & 63;
    const int quad = lane >> 4, l16 = lane & 15;
    const unsigned short* base = ztu + (size_t)bh * 131072;
    const unsigned short* baseT = ztut + (size_t)bh * 131072;

    // Q fragments: 2 row-groups x 2 k-chunks (raw, unscaled)
    const int qb = qt * 128 + wave * 32;
    bf16x8 qa[2][2];
#pragma unroll
    for (int g = 0; g < 2; ++g) {
        qa[g][0] = *(const bf16x8*)(base + (qb + g * 16 + l16) * 64 + quad * 8);
        qa[g][1] = *(const bf16x8*)(base + (qb + g * 16 + l16) * 64 + 32 + quad * 8);
    }

    float lsum[2][4] = {};
    f32x4 o[2][4] = {};

    // staging: tile = 8 chunks of 1KB; wave w stages chunks {2w,2w+1} of K and V.
    // chunk c covers rows c*8+(lane>>3); swizzled source group = (lane&7)^(lane>>3)
    const int c0 = wave * 2, c1 = c0 + 1;
    const int lrow = lane >> 3;
    const int sw = (lane & 7) ^ lrow;
    const unsigned short* gK0 = base + (c0 * 8 + lrow) * 64 + sw * 8;
    const unsigned short* gK1 = base + (c1 * 8 + lrow) * 64 + sw * 8;
    const unsigned short* gV0 = baseT + (size_t)(c0 * 8 + lrow) * 2048 + sw * 8;
    const unsigned short* gV1 = baseT + (size_t)(c1 * 8 + lrow) * 2048 + sw * 8;
    unsigned short* lK0 = &Kt[c0 * 512];
    unsigned short* lK1 = &Kt[c1 * 512];
    unsigned short* lV0 = &Vt[c0 * 512];
    unsigned short* lV1 = &Vt[c1 * 512];
    unsigned short* pw = &Pt[wave][0];

    // swizzled read offsets (elements)
    const int swq = (quad ^ (l16 & 7));
    const int koff0 = l16 * 64 + swq * 8;          // + {nf,df}*1024 per row-group
    const int koff1 = l16 * 64 + (swq ^ 4) * 8;

    for (int t = 0; t < 32; ++t) {
        gl_lds16(gK0 + t * 4096, lK0);
        gl_lds16(gK1 + t * 4096, lK1);
        gl_lds16(gV0 + t * 64, lV0);
        gl_lds16(gV1 + t * 64, lV1);
        __syncthreads();

        // S = Q * K^T  (32 q x 64 keys), C-layout col(key)=l16, row(q)=quad*4+r
        f32x4 s[2][4];
#pragma unroll
        for (int nf = 0; nf < 4; ++nf) {
            bf16x8 kb0 = *(const bf16x8*)&Kt[nf * 1024 + koff0];
            bf16x8 kb1 = *(const bf16x8*)&Kt[nf * 1024 + koff1];
#pragma unroll
            for (int g = 0; g < 2; ++g) {
                f32x4 z = {0.f, 0.f, 0.f, 0.f};
                z = MFMA16(qa[g][0], kb0, z);
                z = MFMA16(qa[g][1], kb1, z);
                s[g][nf] = z;
            }
        }

        // p = exp2(s*QSCALE); per-lane partial sums; packed b64 LDS write.
        // P stored col = 4*l16 + nf  (matches ztut's key permutation)
#pragma unroll
        for (int g = 0; g < 2; ++g) {
#pragma unroll
            for (int r = 0; r < 4; ++r) {
                const float p0 = exp2_raw(s[g][0][r] * QSCALE);
                const float p1 = exp2_raw(s[g][1][r] * QSCALE);
                const float p2 = exp2_raw(s[g][2][r] * QSCALE);
                const float p3 = exp2_raw(s[g][3][r] * QSCALE);
                lsum[g][r] += (p0 + p1) + (p2 + p3);
                uint2 pk;
                pk.x = pk_bf16(p0, p1);
                pk.y = pk_bf16(p2, p3);
                *(uint2*)&pw[(g * 16 + quad * 4 + r) * 72 + l16 * 4] = pk;
            }
        }
        asm volatile("s_waitcnt lgkmcnt(0)" ::: "memory");

        // O += P * V   (B-frag rows = d, swizzled key chunks)
        bf16x8 pa[2][2];
#pragma unroll
        for (int g = 0; g < 2; ++g) {
            pa[g][0] = *(const bf16x8*)&pw[(g * 16 + l16) * 72 + quad * 8];
            pa[g][1] = *(const bf16x8*)&pw[(g * 16 + l16) * 72 + 32 + quad * 8];
        }
#pragma unroll
        for (int df = 0; df < 4; ++df) {
            bf16x8 vb0 = *(const bf16x8*)&Vt[df * 1024 + koff0];
            bf16x8 vb1 = *(const bf16x8*)&Vt[df * 1024 + koff1];
#pragma unroll
            for (int g = 0; g < 2; ++g) {
                o[g][df] = MFMA16(pa[g][0], vb0, o[g][df]);
                o[g][df] = MFMA16(pa[g][1], vb1, o[g][df]);
            }
        }
        __syncthreads();
    }

    // epilogue: reduce l across the 16 key-lanes, then packed b64 stores.
    // ssa stored col = h*64 + 4*l16 + df  (matches wtbf's e permutation)
    const int b = bh >> 4, h = bh & 15;
#pragma unroll
    for (int g = 0; g < 2; ++g) {
#pragma unroll
        for (int r = 0; r < 4; ++r) {
            float v = lsum[g][r];
            v += __shfl_xor(v, 1);
            v += __shfl_xor(v, 2);
            v += __shfl_xor(v, 4);
            v += __shfl_xor(v, 8);
            const float inv = 1.0f / v;
            const int token = b * 2048 + qt * 128 + wave * 32 + g * 16 + quad * 4 + r;
            uint2 pk;
            pk.x = pk_bf16(o[g][0][r] * inv, o[g][1][r] * inv);
            pk.y = pk_bf16(o[g][2][r] * inv, o[g][3][r] * inv);
            *(uint2*)(ssa + (size_t)token * 1024 + h * 64 + l16 * 4) = pk;
        }
    }
}

// ---------- launch ----------
extern "C" void kernel_launch(void* const* d_in, const int* in_sizes, int n_in,
                              void* d_out, int out_size, void* d_ws, size_t ws_size,
                              hipStream_t stream) {
    const float* ZT = (const float*)d_in[0];  // (2,2048,1024)
    const float* W = (const float*)d_in[1];   // (1024,1024)
    float* out = (float*)d_out;               // 2 x 4194304 fp32
    char* ws = (char*)d_ws;

    unsigned short* wbf   = (unsigned short*)(ws);                       // 2 MB
    unsigned short* wtbf  = (unsigned short*)(ws + 2u * 1024 * 1024);    // 2 MB
    unsigned short* ztu   = (unsigned short*)(ws + 4u * 1024 * 1024);    // 8 MB (b,h,n,dh_perm)
    unsigned short* ztut  = (unsigned short*)(ws + 12u * 1024 * 1024);   // 8 MB (b,h,dh,n_perm)
    unsigned short* ssabf = (unsigned short*)(ws + 20u * 1024 * 1024);   // 8 MB (e_perm)

    cvt_w_k<<<256, 256, 0, stream>>>(W, wbf, wtbf);
    // ZTU = ZT @ W^T  (A converted fp32->bf16 in-kernel)
    gemm_bt_k<0><<<512, 256, 0, stream>>>(ZT, nullptr, (const __hip_bfloat16*)wbf, ztu, ztut,
                                          nullptr, nullptr);
    // flash attention, XCD-swizzled
    attn_k<<<512, 256, 0, stream>>>(ztu, ztut, ssabf);
    // mssa = ssa @ W, duplicated output
    gemm_bt_k<1><<<512, 256, 0, stream>>>(nullptr, (const __hip_bfloat16*)ssabf,
                                          (const __hip_bfloat16*)wtbf, nullptr, nullptr, out,
                                          out + 4194304);
}

// Round 7
// 159.077 us; speedup vs baseline: 1.2331x; 1.0232x over previous
//
#include <hip/hip_runtime.h>
#include <hip/hip_bf16.h>
#include <stdint.h>

// ---------- types ----------
typedef __attribute__((ext_vector_type(8))) short bf16x8;   // 8 bf16 in 4 VGPRs
typedef __attribute__((ext_vector_type(4))) float f32x4;

#define MFMA16(a, b, c) __builtin_amdgcn_mfma_f32_16x16x32_bf16(a, b, c, 0, 0, 0)

// async global->LDS, 16 bytes per lane; LDS dest = wave-uniform base + lane*16
typedef const __attribute__((address_space(1))) unsigned int* as1_u32p;
typedef __attribute__((address_space(3))) unsigned int* as3_u32p;
__device__ __forceinline__ void gl_lds16(const void* g, void* l) {
    __builtin_amdgcn_global_load_lds((as1_u32p)g, (as3_u32p)l, 16, 0, 0);
}

__device__ __forceinline__ unsigned short f2bs(float f) {
    __hip_bfloat16 h = __float2bfloat16(f);   // RNE
    unsigned short s;
    __builtin_memcpy(&s, &h, 2);
    return s;
}

// packed RNE f32x2 -> bf16x2 (v_cvt_pk_bf16_f32 on gfx950)
__device__ __forceinline__ unsigned int pk_bf16(float a, float b) {
    float2 f; f.x = a; f.y = b;
    __hip_bfloat162 h = __float22bfloat162_rn(f);
    unsigned int u;
    __builtin_memcpy(&u, &h, 4);
    return u;
}

// raw v_exp_f32: D = 2^S0 (softmax inputs are well in range)
__device__ __forceinline__ float exp2_raw(float x) {
    float r;
    asm("v_exp_f32 %0, %1" : "=v"(r) : "v"(x));
    return r;
}

// combined softmax scale: DH^-0.5 * log2(e); applied to fp32 scores pre-exp
#define QSCALE 0.18033688f

// ---------- W fp32 -> bf16 (straight + natural transpose) ----------
// 256 blocks of 64x64 tiles; wtbf via LDS transpose, coalesced b128 stores.
__global__ __launch_bounds__(256) void cvt_w_k(const float* __restrict__ w,
                                               unsigned short* __restrict__ wbf,
                                               unsigned short* __restrict__ wtbf) {
    __shared__ __attribute__((aligned(16))) unsigned short T[64 * 72];  // 9 KB
    const int b2 = blockIdx.x;               // 256 tiles: 16x16 of 64x64
    const int tid = threadIdx.x;
    const int e0 = (b2 >> 4) * 64, d0 = (b2 & 15) * 64;
    const int el = tid >> 2;                 // 0..63
    const int dl = (tid & 3) * 16;           // 0,16,32,48
    const float* src = w + (size_t)(e0 + el) * 1024 + d0 + dl;
    unsigned short myv[16];
#pragma unroll
    for (int q = 0; q < 4; ++q) {
        const float4 v = *(const float4*)(src + q * 4);
        myv[q * 4 + 0] = f2bs(v.x);
        myv[q * 4 + 1] = f2bs(v.y);
        myv[q * 4 + 2] = f2bs(v.z);
        myv[q * 4 + 3] = f2bs(v.w);
    }
    // wbf straight (two 16B stores)
    *(bf16x8*)(wbf + (size_t)(e0 + el) * 1024 + d0 + dl) = *(const bf16x8*)&myv[0];
    *(bf16x8*)(wbf + (size_t)(e0 + el) * 1024 + d0 + dl + 8) = *(const bf16x8*)&myv[8];
    // LDS transpose: T[d_local][e_local] (natural)
#pragma unroll
    for (int q = 0; q < 16; ++q) T[(dl + q) * 72 + el] = myv[q];
    __syncthreads();
    // coalesced wtbf stores: row d, 64 e contiguous
#pragma unroll
    for (int p = 0; p < 2; ++p) {
        const int idx = p * 256 + tid;
        const int dd = idx >> 3, c = (idx & 7) * 8;
        const bf16x8 v = *(const bf16x8*)&T[dd * 72 + c];
        *(bf16x8*)(wtbf + (size_t)(d0 + dd) * 1024 + e0 + c) = v;
    }
}

// ---------- GEMM: C[M,N] = A[M,K] * B[N,K]^T, tile 64x128, BK=64, 4 waves ----------
// 1D grid 512, XCD-swizzled: xcd = p&7, bm = xcd*8 + ((p>>3)&7), bn = p>>6.
// EPI 0: A staged from fp32 ZT (fused convert); C -> ztu (b,h,n,dh_perm) bf16
//        + ztut via LDS transpose: rows = natural dh, cols = tokens permuted
//        within 32-groups (n32 -> quad*8 + mb*4 + r) for the attn S^T->P^T trick
// EPI 1: A staged from bf16 ssa via gl_lds16; C -> out0, out1 fp32
template <int EPI>
__global__ __launch_bounds__(256, 2) void gemm_bt_k(
    const float* __restrict__ Af32, const __hip_bfloat16* __restrict__ Abf,
    const __hip_bfloat16* __restrict__ B,
    unsigned short* __restrict__ ztu, unsigned short* __restrict__ ztut,
    float* __restrict__ out0, float* __restrict__ out1) {
    __shared__ __attribute__((aligned(16))) unsigned short smem[12288];  // 24 KB
    unsigned short* At = smem;          // [2][64][32]  (h-half major)
    unsigned short* Bt = smem + 4096;   // [2][128][32]
    unsigned short* Tb = smem;          // epilogue reuse: [128][72] = 18 KB

    const int p = blockIdx.x;
    const int bm = (p & 7) * 8 + ((p >> 3) & 7);   // same-bm blocks share an XCD
    const int bn = p >> 6;
    const int tid = threadIdx.x;
    const int wave = tid >> 6, lane = tid & 63;
    const int wm = wave >> 1, wn = wave & 1;   // wave tile: 32 rows x 64 cols
    const int quad = lane >> 4, l16 = lane & 15;

    f32x4 acc[2][4] = {};

    // staging: A rows wave*16+lr; B chunks 2w,2w+1; lane covers (lr, lc..lc+7)
    const int lr = lane >> 2, lc = (lane & 3) * 8;
    const float* Agf = Af32 ? Af32 + (size_t)(bm * 64 + wave * 16 + lr) * 1024 + lc : nullptr;
    const __hip_bfloat16* Agb =
        Abf ? Abf + (size_t)(bm * 64 + wave * 16 + lr) * 1024 + lc : nullptr;
    const __hip_bfloat16* Bg0 = B + (size_t)(bn * 128 + (2 * wave) * 16 + lr) * 1024 + lc;
    const __hip_bfloat16* Bg1 = B + (size_t)(bn * 128 + (2 * wave + 1) * 16 + lr) * 1024 + lc;
    unsigned short* lA = At + wave * 512;
    unsigned short* lB0 = Bt + (2 * wave) * 512;
    unsigned short* lB1 = Bt + (2 * wave + 1) * 512;

    for (int kt = 0; kt < 16; ++kt) {
        const int ko = kt << 6;
        if (EPI == 0) {
            // fused fp32->bf16 A staging
#pragma unroll
            for (int h = 0; h < 2; ++h) {
                const float4 v0 = *(const float4*)(Agf + ko + h * 32);
                const float4 v1 = *(const float4*)(Agf + ko + h * 32 + 4);
                uint4 wv;
                wv.x = pk_bf16(v0.x, v0.y);
                wv.y = pk_bf16(v0.z, v0.w);
                wv.z = pk_bf16(v1.x, v1.y);
                wv.w = pk_bf16(v1.z, v1.w);
                *(uint4*)(lA + h * 2048 + lr * 32 + lc) = wv;
            }
        } else {
            gl_lds16(Agb + ko, lA);
            gl_lds16(Agb + ko + 32, lA + 2048);
        }
        gl_lds16(Bg0 + ko, lB0);
        gl_lds16(Bg0 + ko + 32, lB0 + 4096);
        gl_lds16(Bg1 + ko, lB1);
        gl_lds16(Bg1 + ko + 32, lB1 + 4096);
        __syncthreads();
        bf16x8 af[2][2], bfr[2][4];
#pragma unroll
        for (int h = 0; h < 2; ++h)
#pragma unroll
            for (int i = 0; i < 2; ++i)
                af[h][i] = *(const bf16x8*)&At[h * 2048 + (wm * 32 + i * 16 + l16) * 32 + quad * 8];
#pragma unroll
        for (int h = 0; h < 2; ++h)
#pragma unroll
            for (int j = 0; j < 4; ++j)
                bfr[h][j] = *(const bf16x8*)&Bt[h * 4096 + (wn * 64 + j * 16 + l16) * 32 + quad * 8];
#pragma unroll
        for (int h = 0; h < 2; ++h)
#pragma unroll
            for (int i = 0; i < 2; ++i)
#pragma unroll
                for (int j = 0; j < 4; ++j) acc[i][j] = MFMA16(af[h][i], bfr[h][j], acc[i][j]);
        __syncthreads();
    }

    if (EPI == 0) {
        const int h = bn * 2 + wn;           // e = bn*128 + wn*64 + j*16+l16 -> j-independent
        const int bb = bm >> 5;              // batch
        const int nb = (bm & 31) * 64;       // token base within batch
        const size_t hb = (size_t)(bb * 16 + h) * 131072;
#pragma unroll
        for (int i = 0; i < 2; ++i) {
#pragma unroll
            for (int r = 0; r < 4; ++r) {
                const int n = nb + wm * 32 + i * 16 + quad * 4 + r;
                uint2 pk;
                pk.x = pk_bf16(acc[i][0][r], acc[i][1][r]);
                pk.y = pk_bf16(acc[i][2][r], acc[i][3][r]);
                // ztu: dh stored-permuted (4*l16 + j) -> one packed b64 store
                *(uint2*)(ztu + hb + n * 64 + l16 * 4) = pk;
                // Tb[e_local][np_local]: key perm within 32-groups for S^T trick:
                // n_local = wm*32 + i*16 + quad*4 + r -> np = wm*32 + quad*8 + i*4 + r
                const int npl = wm * 32 + quad * 8 + i * 4 + r;
                Tb[(wn * 64 + 0 + l16) * 72 + npl] = (unsigned short)(pk.x & 0xffff);
                Tb[(wn * 64 + 16 + l16) * 72 + npl] = (unsigned short)(pk.x >> 16);
                Tb[(wn * 64 + 32 + l16) * 72 + npl] = (unsigned short)(pk.y & 0xffff);
                Tb[(wn * 64 + 48 + l16) * 72 + npl] = (unsigned short)(pk.y >> 16);
            }
        }
        __syncthreads();
        // ztut: coalesced b128 stores, rows = natural dh, cols = permuted tokens
#pragma unroll
        for (int ee = 0; ee < 4; ++ee) {
            const int e_local = wave * 32 + ee * 8 + (lane >> 3);
            const int nc = (lane & 7) * 8;
            const bf16x8 v = *(const bf16x8*)&Tb[e_local * 72 + nc];
            const int hh = bn * 2 + (e_local >> 6);
            const int dh = e_local & 63;
            *(bf16x8*)(ztut + (size_t)(bb * 16 + hh) * 131072 + dh * 2048 + nb + nc) = v;
        }
    } else {
#pragma unroll
        for (int i = 0; i < 2; ++i) {
#pragma unroll
            for (int r = 0; r < 4; ++r) {
                const int mm = bm * 64 + wm * 32 + i * 16 + quad * 4 + r;
#pragma unroll
                for (int j = 0; j < 4; ++j) {
                    const int e = bn * 128 + wn * 64 + j * 16 + l16;
                    const float v = acc[i][j][r];
                    out0[(size_t)mm * 1024 + e] = v;
                    out1[(size_t)mm * 1024 + e] = v;
                }
            }
        }
    }
}

// ---------- flash attention, transposed (register-P) structure ----------
// 1D grid 512, XCD-swizzled. 256 threads = 4 waves; each wave owns 32 q-rows.
// S^T = K*Q^T (K as A-operand, Q as B-operand). With ztut's key permutation,
// each lane's S^T C-values are exactly its P^T B-fragment for O^T = V^T*P^T:
// exp+pack in registers -> NO LDS round-trip for P. O^T C-layout gives
// natural-dh packed b64 ssa stores. LDS = Kt+Vt only (16 KB).
__global__ __launch_bounds__(256, 2) void attn_k(const unsigned short* __restrict__ ztu,
                                                 const unsigned short* __restrict__ ztut,
                                                 unsigned short* __restrict__ ssa) {
    __shared__ __attribute__((aligned(16))) unsigned short Kt[64 * 64];   // [key][d-sw]
    __shared__ __attribute__((aligned(16))) unsigned short Vt[64 * 64];   // [d][key'-sw]
    const int p = blockIdx.x;
    const int ii = p >> 3;
    const int bh = (p & 7) * 4 + (ii >> 4);
    const int qt = ii & 15;
    const int tid = threadIdx.x, wave = tid >> 6, lane = tid & 63;
    const int quad = lane >> 4, l16 = lane & 15;
    const unsigned short* base = ztu + (size_t)bh * 131072;
    const unsigned short* baseT = ztut + (size_t)bh * 131072;

    // Q fragments (B-operand): 2 row-groups x 2 k-chunks
    const int qb = qt * 128 + wave * 32;
    bf16x8 qa[2][2];
#pragma unroll
    for (int g = 0; g < 2; ++g) {
        qa[g][0] = *(const bf16x8*)(base + (qb + g * 16 + l16) * 64 + quad * 8);
        qa[g][1] = *(const bf16x8*)(base + (qb + g * 16 + l16) * 64 + 32 + quad * 8);
    }

    float lsum[2] = {0.f, 0.f};
    f32x4 o[2][4] = {};

    // staging: tile = 8 chunks of 1KB; wave w stages chunks {2w,2w+1} of K and V.
    // chunk c covers rows c*8+(lane>>3); swizzled source group = (lane&7)^(lane>>3)
    const int c0 = wave * 2, c1 = c0 + 1;
    const int lrow = lane >> 3;
    const int sw = (lane & 7) ^ lrow;
    const unsigned short* gK0 = base + (c0 * 8 + lrow) * 64 + sw * 8;
    const unsigned short* gK1 = base + (c1 * 8 + lrow) * 64 + sw * 8;
    const unsigned short* gV0 = baseT + (size_t)(c0 * 8 + lrow) * 2048 + sw * 8;
    const unsigned short* gV1 = baseT + (size_t)(c1 * 8 + lrow) * 2048 + sw * 8;
    unsigned short* lK0 = &Kt[c0 * 512];
    unsigned short* lK1 = &Kt[c1 * 512];
    unsigned short* lV0 = &Vt[c0 * 512];
    unsigned short* lV1 = &Vt[c1 * 512];

    // swizzled read offsets (elements)
    const int swq = (quad ^ (l16 & 7));
    const int koff0 = l16 * 64 + swq * 8;          // + {nf,df}*1024 per row-group
    const int koff1 = l16 * 64 + (swq ^ 4) * 8;

    for (int t = 0; t < 32; ++t) {
        gl_lds16(gK0 + t * 4096, lK0);
        gl_lds16(gK1 + t * 4096, lK1);
        gl_lds16(gV0 + t * 64, lV0);
        gl_lds16(gV1 + t * 64, lV1);
        __syncthreads();

        // S^T = K * Q^T: C[m=key nf*16+quad*4+r][n=q=l16], per g
        f32x4 st[2][4];
#pragma unroll
        for (int nf = 0; nf < 4; ++nf) {
            bf16x8 kb0 = *(const bf16x8*)&Kt[nf * 1024 + koff0];
            bf16x8 kb1 = *(const bf16x8*)&Kt[nf * 1024 + koff1];
#pragma unroll
            for (int g = 0; g < 2; ++g) {
                f32x4 z = {0.f, 0.f, 0.f, 0.f};
                z = MFMA16(kb0, qa[g][0], z);
                z = MFMA16(kb1, qa[g][1], z);
                st[g][nf] = z;
            }
        }

        // exp in registers; pack P^T B-fragments: key' = quad*8 + mb*4 + r
        bf16x8 pa[2][2];
#pragma unroll
        for (int g = 0; g < 2; ++g) {
            float e[16];
#pragma unroll
            for (int nf = 0; nf < 4; ++nf)
#pragma unroll
                for (int r = 0; r < 4; ++r) e[nf * 4 + r] = exp2_raw(st[g][nf][r] * QSCALE);
            float s0 = 0.f, s1 = 0.f;
#pragma unroll
            for (int q = 0; q < 8; ++q) { s0 += e[q]; s1 += e[q + 8]; }
            lsum[g] += s0 + s1;
            uint4 u0, u1;
            u0.x = pk_bf16(e[0], e[1]);   u0.y = pk_bf16(e[2], e[3]);
            u0.z = pk_bf16(e[4], e[5]);   u0.w = pk_bf16(e[6], e[7]);
            u1.x = pk_bf16(e[8], e[9]);   u1.y = pk_bf16(e[10], e[11]);
            u1.z = pk_bf16(e[12], e[13]); u1.w = pk_bf16(e[14], e[15]);
            __builtin_memcpy(&pa[g][0], &u0, 16);
            __builtin_memcpy(&pa[g][1], &u1, 16);
        }

        // O^T += V^T * P^T: A = Vt[d][key'-sw], B = pa (registers)
#pragma unroll
        for (int df = 0; df < 4; ++df) {
            bf16x8 vb0 = *(const bf16x8*)&Vt[df * 1024 + koff0];
            bf16x8 vb1 = *(const bf16x8*)&Vt[df * 1024 + koff1];
#pragma unroll
            for (int g = 0; g < 2; ++g) {
                o[g][df] = MFMA16(vb0, pa[g][0], o[g][df]);
                o[g][df] = MFMA16(vb1, pa[g][1], o[g][df]);
            }
        }
        __syncthreads();
    }

    // epilogue: reduce l across quads (keys), then packed b64 natural-dh stores.
    const int b = bh >> 4, h = bh & 15;
#pragma unroll
    for (int g = 0; g < 2; ++g) {
        float v = lsum[g];
        v += __shfl_xor(v, 16);
        v += __shfl_xor(v, 32);
        const float inv = 1.0f / v;
        const int token = b * 2048 + qb + g * 16 + l16;
#pragma unroll
        for (int df = 0; df < 4; ++df) {
            uint2 pk;
            pk.x = pk_bf16(o[g][df][0] * inv, o[g][df][1] * inv);
            pk.y = pk_bf16(o[g][df][2] * inv, o[g][df][3] * inv);
            *(uint2*)(ssa + (size_t)token * 1024 + h * 64 + df * 16 + quad * 4) = pk;
        }
    }
}

// ---------- launch ----------
extern "C" void kernel_launch(void* const* d_in, const int* in_sizes, int n_in,
                              void* d_out, int out_size, void* d_ws, size_t ws_size,
                              hipStream_t stream) {
    const float* ZT = (const float*)d_in[0];  // (2,2048,1024)
    const float* W = (const float*)d_in[1];   // (1024,1024)
    float* out = (float*)d_out;               // 2 x 4194304 fp32
    char* ws = (char*)d_ws;

    unsigned short* wbf   = (unsigned short*)(ws);                       // 2 MB
    unsigned short* wtbf  = (unsigned short*)(ws + 2u * 1024 * 1024);    // 2 MB
    unsigned short* ztu   = (unsigned short*)(ws + 4u * 1024 * 1024);    // 8 MB (b,h,n,dh_perm)
    unsigned short* ztut  = (unsigned short*)(ws + 12u * 1024 * 1024);   // 8 MB (b,h,dh,n_perm32)
    unsigned short* ssabf = (unsigned short*)(ws + 20u * 1024 * 1024);   // 8 MB (natural)

    cvt_w_k<<<256, 256, 0, stream>>>(W, wbf, wtbf);
    // ZTU = ZT @ W^T  (A converted fp32->bf16 in-kernel)
    gemm_bt_k<0><<<512, 256, 0, stream>>>(ZT, nullptr, (const __hip_bfloat16*)wbf, ztu, ztut,
                                          nullptr, nullptr);
    // flash attention, XCD-swizzled, register-P transposed structure
    attn_k<<<512, 256, 0, stream>>>(ztu, ztut, ssabf);
    // mssa = ssa @ W, duplicated output
    gemm_bt_k<1><<<512, 256, 0, stream>>>(nullptr, (const __hip_bfloat16*)ssabf,
                                          (const __hip_bfloat16*)wtbf, nullptr, nullptr, out,
                                          out + 4194304);
}